// Round 6
// baseline (243.364 us; speedup 1.0000x reference)
//
#include <hip/hip_runtime.h>

// ws layout (floats):
//   [128..202]       quantized w_conv (75)
//   [256..44159]     quantized w_fc1 TRANSPOSED [j=343][o=128]
//   [44160..44671]   quantized w_fc2 [4][128]
#define WS_WCONV   128
#define WS_W1T     256
#define WS_W2      44160

__device__ __forceinline__ float q4(float w, float s) {
  if (s <= 0.f) return 0.f;
  float r = rintf(w / s);                     // round-half-even == jnp.round
  r = fminf(fmaxf(r, -8.f), 7.f);
  return r * s;
}

// Single quant dispatch (R3-proven, absmax 0): every fc1 block redundantly
// computes global max|w1| (172 KB, L2/LLC-cheap). Block 88: conv + fc2.
__global__ __launch_bounds__(256) void quant_all(
    const float* __restrict__ wconv, const float* __restrict__ w1,
    const float* __restrict__ w2, float* __restrict__ ws) {
  __shared__ float red[256];
  int b = blockIdx.x, t = threadIdx.x;
  if (b < 88) {
    const float4* w4 = (const float4*)w1;     // 43904/4 == 10976
    float m = 0.f;
    for (int i = t; i < 10976; i += 256) {
      float4 v = w4[i];
      m = fmaxf(m, fmaxf(fmaxf(fabsf(v.x), fabsf(v.y)),
                         fmaxf(fabsf(v.z), fabsf(v.w))));
    }
    red[t] = m;
    __syncthreads();
    for (int s = 128; s > 0; s >>= 1) {
      if (t < s) red[t] = fmaxf(red[t], red[t + s]);
      __syncthreads();
    }
    float s = red[0] * (1.0f / 7.0f);
    #pragma unroll
    for (int k = 0; k < 2; ++k) {
      int idx = b * 512 + k * 256 + t;
      if (idx < 43904) {
        float q = q4(w1[idx], s);
        int o = idx / 343;
        int j = idx - o * 343;
        ws[WS_W1T + j * 128 + o] = q;         // transpose for coalesced FC1
      }
    }
  } else {
    float mc = (t < 75) ? fabsf(wconv[t]) : 0.f;
    float m2 = 0.f;
    for (int i = t; i < 512; i += 256) m2 = fmaxf(m2, fabsf(w2[i]));
    red[t] = mc;
    __syncthreads();
    for (int s = 128; s > 0; s >>= 1) {
      if (t < s) red[t] = fmaxf(red[t], red[t + s]);
      __syncthreads();
    }
    float sc = red[0] * (1.0f / 7.0f);
    __syncthreads();
    red[t] = m2;
    __syncthreads();
    for (int s = 128; s > 0; s >>= 1) {
      if (t < s) red[t] = fmaxf(red[t], red[t + s]);
      __syncthreads();
    }
    float s2 = red[0] * (1.0f / 7.0f);
    if (t < 75) ws[WS_WCONV + t] = q4(wconv[t], sc);
    #pragma unroll
    for (int k = 0; k < 2; ++k) {
      int idx = k * 256 + t;
      ws[WS_W2 + idx] = q4(w2[idx], s2);
    }
  }
}

// 16-byte load with only 4-byte alignment guarantee (global rows stride 31).
struct __align__(4) f4u { float x, y, z, w; };

// Conv+pool straight from GLOBAL memory (no LDS for x). Global x layout
// [31][16][31]: depth stride 496, h stride 31 — identical indices to the
// proven LDS version, base0 = pd*1984 + ph*62 + pw*4. Each (dd,hh) row's
// 7-float window = two overlapping 16B loads (L1/L2-hot; block working set
// 61.5 KB). fma order byte-identical to R0 -> absmax 0.
__device__ __forceinline__ void conv_global(
    const float* __restrict__ xb, const float* __restrict__ wq,
    int t, float bc, float* __restrict__ feat) {
  if (t >= 343) return;
  int pdl = t / 49;
  int rr  = t - pdl * 49;
  int ph  = rr / 7;
  int pw  = rr - ph * 7;
  float c[2][2][2];                           // [odp][ohp][owp]
  #pragma unroll
  for (int i = 0; i < 8; ++i) ((float*)c)[i] = 0.f;
  const float* b0 = xb + pdl * 1984 + ph * 62 + pw * 4;
  #pragma unroll
  for (int dd = 0; dd < 7; ++dd) {
    const float* rb = b0 + dd * 496;
    #pragma unroll
    for (int hh = 0; hh < 4; ++hh) {
      const float* rp = rb + hh * 31;
      f4u A = *(const f4u*)rp;                // floats 4pw .. 4pw+3
      f4u B = *(const f4u*)(rp + 3);          // floats 4pw+3 .. 4pw+6 (<=30)
      float row[7] = {A.x, A.y, A.z, A.w, B.y, B.z, B.w};
      #pragma unroll
      for (int odp = 0; odp < 2; ++odp) {
        int kd = dd - 2 * odp;
        if (kd < 0 || kd > 4) continue;       // folds at compile time
        #pragma unroll
        for (int ohp = 0; ohp < 2; ++ohp) {
          int kh = hh - ohp;
          if (kh < 0 || kh > 2) continue;     // folds at compile time
          #pragma unroll
          for (int owp = 0; owp < 2; ++owp) {
            float a = c[odp][ohp][owp];
            #pragma unroll
            for (int kw = 0; kw < 5; ++kw)
              a = fmaf(row[2 * owp + kw], wq[kd * 15 + kh * 5 + kw], a);
            c[odp][ohp][owp] = a;
          }
        }
      }
    }
  }
  float m = ((float*)c)[0];
  #pragma unroll
  for (int i = 1; i < 8; ++i) m = fmaxf(m, ((float*)c)[i]);
  feat[pdl * 49 + rr] = m + bc;
}

// Fused net, zero-LDS-x structure: conv (one 343-thread phase, global->FMA)
// -> feat (2.4 KB LDS) -> FC1 -> FC2 -> softmax. No staging loops, no
// staging barriers, no x bank conflicts. 384 thr = 6 waves; ~5 blocks/CU
// (wave-limited), LDS trivial. 4 barriers total.
__global__ __launch_bounds__(384, 6) void fused_net(
    const float* __restrict__ x, const float* __restrict__ bconv,
    const float* __restrict__ ws, const float* __restrict__ bfc1,
    const float* __restrict__ bfc2, float* __restrict__ out) {
  __shared__ alignas(16) float feat[344];     // +1: feat[343]=0 pads FC1 quads
  __shared__ alignas(16) float fc1p[128];
  __shared__ alignas(16) float a1[128];
  __shared__ float s2[4];
  int t = threadIdx.x;
  int b = blockIdx.x;
  const float* wq = ws + WS_WCONV;
  float bc = bconv[0];
  const float* xb = x + (size_t)b * 15376;

  // P1: conv+pool, all 343 pooled outputs, straight from global
  if (t == 383) feat[343] = 0.f;
  conv_global(xb, wq, t, bc, feat);
  __syncthreads();

  // P2: FC1 (343->128) on t<256, exact R0 math (halves at j=172; g=1 tail
  // uses feat[343]=0, w1T row 343 lands in finite W2 region * 0.0 -> exact).
  int g = (t >> 7) & 1, o = t & 127;
  float acc = 0.f;
  if (t < 256) {
    const float* w1T = ws + WS_W1T;
    int j0 = g ? 172 : 0;
    const float4* f4 = (const float4*)&feat[j0];
    const float* wp = w1T + j0 * 128 + o;
    float q0 = 0.f, q1 = 0.f, q2 = 0.f, q3 = 0.f;
    for (int q = 0; q < 43; ++q) {
      float4 ff = f4[q];
      q0 = fmaf(ff.x, wp[0],   q0);
      q1 = fmaf(ff.y, wp[128], q1);
      q2 = fmaf(ff.z, wp[256], q2);
      q3 = fmaf(ff.w, wp[384], q3);
      wp += 512;
    }
    acc = (q0 + q1) + (q2 + q3);
    if (g) fc1p[o] = acc;
  }
  __syncthreads();
  if (t < 256 && !g) a1[o] = fmaxf(acc + fc1p[o] + bfc1[o], 0.f);
  __syncthreads();

  // P3: FC2 (128->4) on one wave: lane = (kk,cls), shuffle-reduce over kk.
  if (t < 64) {
    int cls = t & 3, kk = t >> 2;             // kk 0..15, 8 k's each
    const float* w2p = ws + WS_W2 + cls * 128 + kk * 8;
    const float* av = a1 + kk * 8;
    float p = 0.f;
    #pragma unroll
    for (int i = 0; i < 8; ++i) p = fmaf(av[i], w2p[i], p);
    p += __shfl_down(p, 32);
    p += __shfl_down(p, 16);
    p += __shfl_down(p, 8);
    p += __shfl_down(p, 4);
    if (t < 4) s2[t] = p + bfc2[t];
  }
  __syncthreads();
  // P4: softmax + store
  if (t < 4) {
    float v0 = s2[0], v1 = s2[1], v2 = s2[2], v3 = s2[3];
    float m = fmaxf(fmaxf(v0, v1), fmaxf(v2, v3));
    float e0 = expf(v0 - m), e1 = expf(v1 - m);
    float e2 = expf(v2 - m), e3 = expf(v3 - m);
    float inv = 1.f / (e0 + e1 + e2 + e3);
    float mine = (t == 0) ? e0 : (t == 1) ? e1 : (t == 2) ? e2 : e3;
    out[b * 4 + t] = mine * inv;
  }
}

extern "C" void kernel_launch(void* const* d_in, const int* in_sizes, int n_in,
                              void* d_out, int out_size, void* d_ws, size_t ws_size,
                              hipStream_t stream) {
  const float* x     = (const float*)d_in[0];
  const float* wconv = (const float*)d_in[1];
  const float* bconv = (const float*)d_in[2];
  const float* wfc1  = (const float*)d_in[3];
  const float* bfc1  = (const float*)d_in[4];
  const float* wfc2  = (const float*)d_in[5];
  const float* bfc2  = (const float*)d_in[6];
  float* out = (float*)d_out;
  float* ws  = (float*)d_ws;

  quant_all<<<89, 256, 0, stream>>>(wconv, wfc1, wfc2, ws);
  fused_net<<<2048, 384, 0, stream>>>(x, bconv, ws, bfc1, bfc2, out);
}

// Round 7
// 231.721 us; speedup vs baseline: 1.0502x; 1.0502x over previous
//
#include <hip/hip_runtime.h>

// ws layout (floats):
//   [128..202]       quantized w_conv (75)
//   [256..44159]     quantized w_fc1 TRANSPOSED [j=343][o=128]
//   [44160..44671]   quantized w_fc2 [4][128]
//   [45056..749567]  feat [2048][344] (pooled conv outputs, +pad col = 0)
#define WS_WCONV   128
#define WS_W1T     256
#define WS_W2      44160
#define WS_FEAT    45056

__device__ __forceinline__ float q4(float w, float s) {
  if (s <= 0.f) return 0.f;
  float r = rintf(w / s);                     // round-half-even == jnp.round
  r = fminf(fmaxf(r, -8.f), 7.f);
  return r * s;
}

// Single quant dispatch (proven, absmax 0): every fc1 block redundantly
// computes global max|w1| (172 KB, L2/LLC-cheap). Block 88: conv + fc2.
__global__ __launch_bounds__(256) void quant_all(
    const float* __restrict__ wconv, const float* __restrict__ w1,
    const float* __restrict__ w2, float* __restrict__ ws) {
  __shared__ float red[256];
  int b = blockIdx.x, t = threadIdx.x;
  if (b < 88) {
    const float4* w4 = (const float4*)w1;     // 43904/4 == 10976
    float m = 0.f;
    for (int i = t; i < 10976; i += 256) {
      float4 v = w4[i];
      m = fmaxf(m, fmaxf(fmaxf(fabsf(v.x), fabsf(v.y)),
                         fmaxf(fabsf(v.z), fabsf(v.w))));
    }
    red[t] = m;
    __syncthreads();
    for (int s = 128; s > 0; s >>= 1) {
      if (t < s) red[t] = fmaxf(red[t], red[t + s]);
      __syncthreads();
    }
    float s = red[0] * (1.0f / 7.0f);
    #pragma unroll
    for (int k = 0; k < 2; ++k) {
      int idx = b * 512 + k * 256 + t;
      if (idx < 43904) {
        float q = q4(w1[idx], s);
        int o = idx / 343;
        int j = idx - o * 343;
        ws[WS_W1T + j * 128 + o] = q;         // transpose for coalesced FC1
      }
    }
  } else {
    float mc = (t < 75) ? fabsf(wconv[t]) : 0.f;
    float m2 = 0.f;
    for (int i = t; i < 512; i += 256) m2 = fmaxf(m2, fabsf(w2[i]));
    red[t] = mc;
    __syncthreads();
    for (int s = 128; s > 0; s >>= 1) {
      if (t < s) red[t] = fmaxf(red[t], red[t + s]);
      __syncthreads();
    }
    float sc = red[0] * (1.0f / 7.0f);
    __syncthreads();
    red[t] = m2;
    __syncthreads();
    for (int s = 128; s > 0; s >>= 1) {
      if (t < s) red[t] = fmaxf(red[t], red[t + s]);
      __syncthreads();
    }
    float s2 = red[0] * (1.0f / 7.0f);
    if (t < 75) ws[WS_WCONV + t] = q4(wconv[t], sc);
    #pragma unroll
    for (int k = 0; k < 2; ++k) {
      int idx = k * 256 + t;
      ws[WS_W2 + idx] = q4(w2[idx], s2);
    }
  }
}

// 16-byte load with only 4-byte alignment guarantee (global rows stride 31).
struct __align__(4) f4u { float x, y, z, w; };

// Conv+pool, one pooled output per thread, straight from global (R6-proven
// math/loads, absmax 0). Flat gid over 2048*343 = 702464 = 2744*256 outputs:
// no guard, no LDS, no barriers -> full-occupancy streaming; L1/L2 latency
// hidden by TLP (up to 32 waves/CU).
__global__ __launch_bounds__(256, 8) void conv_pool(
    const float* __restrict__ x, const float* __restrict__ bconv,
    const float* __restrict__ ws, float* __restrict__ feat_g) {
  int gid = blockIdx.x * 256 + threadIdx.x;
  // batch = gid/343 (magic exact for gid < 8.5M), rr = gid%343
  int batch = (int)(((unsigned long long)(unsigned)gid * 12521772ull) >> 32);
  int rr = gid - batch * 343;
  int pdl = (rr * 1338) >> 16;                // rr/49, exact rr<2520
  int r2  = rr - pdl * 49;
  int ph  = (r2 * 9363) >> 16;                // r2/7, exact r2<49
  int pw  = r2 - ph * 7;
  const float* wq = ws + WS_WCONV;
  float bc = bconv[0];
  const float* xb = x + (size_t)batch * 15376;
  float c[2][2][2];                           // [odp][ohp][owp]
  #pragma unroll
  for (int i = 0; i < 8; ++i) ((float*)c)[i] = 0.f;
  const float* b0 = xb + pdl * 1984 + ph * 62 + pw * 4;
  #pragma unroll
  for (int dd = 0; dd < 7; ++dd) {
    const float* rb = b0 + dd * 496;
    #pragma unroll
    for (int hh = 0; hh < 4; ++hh) {
      const float* rp = rb + hh * 31;
      f4u A = *(const f4u*)rp;                // floats 4pw .. 4pw+3
      f4u B = *(const f4u*)(rp + 3);          // floats 4pw+3 .. 4pw+6 (<=30)
      float row[7] = {A.x, A.y, A.z, A.w, B.y, B.z, B.w};
      #pragma unroll
      for (int odp = 0; odp < 2; ++odp) {
        int kd = dd - 2 * odp;
        if (kd < 0 || kd > 4) continue;       // folds at compile time
        #pragma unroll
        for (int ohp = 0; ohp < 2; ++ohp) {
          int kh = hh - ohp;
          if (kh < 0 || kh > 2) continue;     // folds at compile time
          #pragma unroll
          for (int owp = 0; owp < 2; ++owp) {
            float a = c[odp][ohp][owp];
            #pragma unroll
            for (int kw = 0; kw < 5; ++kw)
              a = fmaf(row[2 * owp + kw], wq[kd * 15 + kh * 5 + kw], a);
            c[odp][ohp][owp] = a;
          }
        }
      }
    }
  }
  float m = ((float*)c)[0];
  #pragma unroll
  for (int i = 1; i < 8; ++i) m = fmaxf(m, ((float*)c)[i]);
  feat_g[(size_t)batch * 344 + rr] = m + bc;
  if (rr == 0) feat_g[(size_t)batch * 344 + 343] = 0.f;  // pad for FC1 quads
}

// FC1+FC2+softmax, 4 batches per block (512 blocks). w1T quad loaded once,
// fma'd into 4 batch accumulators -> 1/4 the w1T cache traffic. Per-batch
// fma order byte-identical to the proven kernel -> absmax 0.
__global__ __launch_bounds__(256) void fc_net(
    const float* __restrict__ ws, const float* __restrict__ bfc1,
    const float* __restrict__ bfc2, float* __restrict__ out) {
  __shared__ alignas(16) float feat[4][344];
  __shared__ float fc1p[4][128];
  __shared__ float a1[4][128];
  __shared__ float s2[4][4];
  int t = threadIdx.x;
  int b0 = blockIdx.x * 4;

  // stage 4 batches' feat (344 f4) -> LDS
  {
    const float4* src = (const float4*)(ws + WS_FEAT + (size_t)b0 * 344);
    float4* dst = (float4*)&feat[0][0];
    for (int i = t; i < 344; i += 256) dst[i] = src[i];
  }
  __syncthreads();

  // FC1: g = j-half, o = output; 43 quads per half (g=1 tail uses
  // feat[343]=0; w1T row 343 lands in finite W2 region * 0.0 -> exact).
  int g = t >> 7, o = t & 127;
  {
    const float* wp = ws + WS_W1T + (g ? 172 * 128 : 0) + o;
    int j0 = g ? 172 : 0;
    float q0[4], q1[4], q2[4], q3[4];
    #pragma unroll
    for (int bb = 0; bb < 4; ++bb) { q0[bb] = q1[bb] = q2[bb] = q3[bb] = 0.f; }
    for (int k = 0; k < 43; ++k) {
      float w0 = wp[0], w1 = wp[128], w2 = wp[256], w3 = wp[384];
      #pragma unroll
      for (int bb = 0; bb < 4; ++bb) {
        float4 ff = *(const float4*)&feat[bb][j0 + k * 4];
        q0[bb] = fmaf(ff.x, w0, q0[bb]);
        q1[bb] = fmaf(ff.y, w1, q1[bb]);
        q2[bb] = fmaf(ff.z, w2, q2[bb]);
        q3[bb] = fmaf(ff.w, w3, q3[bb]);
      }
      wp += 512;
    }
    #pragma unroll
    for (int bb = 0; bb < 4; ++bb) {
      float acc = (q0[bb] + q1[bb]) + (q2[bb] + q3[bb]);
      if (g) fc1p[bb][o] = acc;
      else   a1[bb][o] = acc;                 // partial; finished below
    }
    __syncthreads();
    #pragma unroll
    for (int bb = 0; bb < 4; ++bb)
      if (!g) a1[bb][o] = fmaxf(a1[bb][o] + fc1p[bb][o] + bfc1[o], 0.f);
  }
  __syncthreads();

  // FC2: wave w handles batch w; lane l=(kk,cls), shuffle-reduce over kk.
  {
    int w = t >> 6, l = t & 63;
    int cls = l & 3, kk = l >> 2;             // kk 0..15, 8 k's each
    const float* w2p = ws + WS_W2 + cls * 128 + kk * 8;
    const float* av = &a1[w][kk * 8];
    float p = 0.f;
    #pragma unroll
    for (int i = 0; i < 8; ++i) p = fmaf(av[i], w2p[i], p);
    p += __shfl_down(p, 32);
    p += __shfl_down(p, 16);
    p += __shfl_down(p, 8);
    p += __shfl_down(p, 4);
    if (l < 4) s2[w][l] = p + bfc2[l];
  }
  __syncthreads();
  // softmax + store: thread t<16 -> (batch w, class cls)
  if (t < 16) {
    int w = t >> 2, cls = t & 3;
    float v0 = s2[w][0], v1 = s2[w][1], v2 = s2[w][2], v3 = s2[w][3];
    float m = fmaxf(fmaxf(v0, v1), fmaxf(v2, v3));
    float e0 = expf(v0 - m), e1 = expf(v1 - m);
    float e2 = expf(v2 - m), e3 = expf(v3 - m);
    float inv = 1.f / (e0 + e1 + e2 + e3);
    float mine = (cls == 0) ? e0 : (cls == 1) ? e1 : (cls == 2) ? e2 : e3;
    out[(b0 + w) * 4 + cls] = mine * inv;
  }
}

extern "C" void kernel_launch(void* const* d_in, const int* in_sizes, int n_in,
                              void* d_out, int out_size, void* d_ws, size_t ws_size,
                              hipStream_t stream) {
  const float* x     = (const float*)d_in[0];
  const float* wconv = (const float*)d_in[1];
  const float* bconv = (const float*)d_in[2];
  const float* wfc1  = (const float*)d_in[3];
  const float* bfc1  = (const float*)d_in[4];
  const float* wfc2  = (const float*)d_in[5];
  const float* bfc2  = (const float*)d_in[6];
  float* out = (float*)d_out;
  float* ws  = (float*)d_ws;

  quant_all<<<89, 256, 0, stream>>>(wconv, wfc1, wfc2, ws);
  conv_pool<<<2744, 256, 0, stream>>>(x, bconv, ws, ws + WS_FEAT);
  fc_net<<<512, 256, 0, stream>>>(ws, bfc1, bfc2, out);
}

// Round 9
// 228.183 us; speedup vs baseline: 1.0665x; 1.0155x over previous
//
#include <hip/hip_runtime.h>

// ws layout (floats):
//   [128..202]       quantized w_conv (75)
//   [256..44159]     quantized w_fc1 TRANSPOSED [j=343][o=128]
//   [44160..44671]   quantized w_fc2 [4][128]
//   [45056..749567]  feat [2048][344] (pooled conv outputs, +pad col = 0)
#define WS_WCONV   128
#define WS_W1T     256
#define WS_W2      44160
#define WS_FEAT    45056

__device__ __forceinline__ float q4(float w, float s) {
  if (s <= 0.f) return 0.f;
  float r = rintf(w / s);                     // round-half-even == jnp.round
  r = fminf(fmaxf(r, -8.f), 7.f);
  return r * s;
}

// Single quant dispatch (proven, absmax 0): every fc1 block redundantly
// computes global max|w1| (172 KB, L2/LLC-cheap). Block 88: conv + fc2.
__global__ __launch_bounds__(256) void quant_all(
    const float* __restrict__ wconv, const float* __restrict__ w1,
    const float* __restrict__ w2, float* __restrict__ ws) {
  __shared__ float red[256];
  int b = blockIdx.x, t = threadIdx.x;
  if (b < 88) {
    const float4* w4 = (const float4*)w1;     // 43904/4 == 10976
    float m = 0.f;
    for (int i = t; i < 10976; i += 256) {
      float4 v = w4[i];
      m = fmaxf(m, fmaxf(fmaxf(fabsf(v.x), fabsf(v.y)),
                         fmaxf(fabsf(v.z), fabsf(v.w))));
    }
    red[t] = m;
    __syncthreads();
    for (int s = 128; s > 0; s >>= 1) {
      if (t < s) red[t] = fmaxf(red[t], red[t + s]);
      __syncthreads();
    }
    float s = red[0] * (1.0f / 7.0f);
    #pragma unroll
    for (int k = 0; k < 2; ++k) {
      int idx = b * 512 + k * 256 + t;
      if (idx < 43904) {
        float q = q4(w1[idx], s);
        int o = idx / 343;
        int j = idx - o * 343;
        ws[WS_W1T + j * 128 + o] = q;         // transpose for coalesced FC1
      }
    }
  } else {
    float mc = (t < 75) ? fabsf(wconv[t]) : 0.f;
    float m2 = 0.f;
    for (int i = t; i < 512; i += 256) m2 = fmaxf(m2, fabsf(w2[i]));
    red[t] = mc;
    __syncthreads();
    for (int s = 128; s > 0; s >>= 1) {
      if (t < s) red[t] = fmaxf(red[t], red[t + s]);
      __syncthreads();
    }
    float sc = red[0] * (1.0f / 7.0f);
    __syncthreads();
    red[t] = m2;
    __syncthreads();
    for (int s = 128; s > 0; s >>= 1) {
      if (t < s) red[t] = fmaxf(red[t], red[t + s]);
      __syncthreads();
    }
    float s2 = red[0] * (1.0f / 7.0f);
    if (t < 75) ws[WS_WCONV + t] = q4(wconv[t], sc);
    #pragma unroll
    for (int k = 0; k < 2; ++k) {
      int idx = k * 256 + t;
      ws[WS_W2 + idx] = q4(w2[idx], s2);
    }
  }
}

// 16-byte load with only 4-byte alignment guarantee (global rows stride 31).
struct __align__(4) f4u { float x, y, z, w; };

// Conv+pool, one pooled output per thread, straight from global (R6/R7-
// proven math, absmax 0). R7 lesson: under (256,8) the compiler allocated
// 36 VGPRs -> ~zero loads in flight -> latency-serialized. Now (256,4)
// [128 VGPR budget] + explicit dd-software-pipeline: double-buffered row
// loads for depth dd+1 issue before dd's ~86 FMAs. buf indices are all
// compile-time under full unroll (no scratch).
__global__ __launch_bounds__(256, 4) void conv_pool(
    const float* __restrict__ x, const float* __restrict__ bconv,
    const float* __restrict__ ws, float* __restrict__ feat_g) {
  int gid = blockIdx.x * 256 + threadIdx.x;
  // batch = gid/343 (magic exact for gid < 8.5M), rr = gid%343
  int batch = (int)(((unsigned long long)(unsigned)gid * 12521772ull) >> 32);
  int rr = gid - batch * 343;
  int pdl = (rr * 1338) >> 16;                // rr/49, exact rr<2520
  int r2  = rr - pdl * 49;
  int ph  = (r2 * 9363) >> 16;                // r2/7, exact r2<49
  int pw  = r2 - ph * 7;
  const float* wq = ws + WS_WCONV;
  float bc = bconv[0];
  const float* xb = x + (size_t)batch * 15376;
  float c[2][2][2];                           // [odp][ohp][owp]
  #pragma unroll
  for (int i = 0; i < 8; ++i) ((float*)c)[i] = 0.f;
  const float* b0 = xb + pdl * 1984 + ph * 62 + pw * 4;

  f4u buf[2][4][2];                           // [dd&1][hh][lo/hi]
  #pragma unroll
  for (int hh = 0; hh < 4; ++hh) {            // preload dd = 0
    const float* rp = b0 + hh * 31;
    buf[0][hh][0] = *(const f4u*)rp;
    buf[0][hh][1] = *(const f4u*)(rp + 3);
  }
  #pragma unroll
  for (int dd = 0; dd < 7; ++dd) {
    if (dd < 6) {                             // issue next depth's 8 loads
      const float* rb = b0 + (dd + 1) * 496;
      #pragma unroll
      for (int hh = 0; hh < 4; ++hh) {
        const float* rp = rb + hh * 31;
        buf[(dd + 1) & 1][hh][0] = *(const f4u*)rp;
        buf[(dd + 1) & 1][hh][1] = *(const f4u*)(rp + 3);
      }
    }
    #pragma unroll
    for (int hh = 0; hh < 4; ++hh) {
      f4u A = buf[dd & 1][hh][0];             // floats 4pw .. 4pw+3
      f4u B = buf[dd & 1][hh][1];             // floats 4pw+3 .. 4pw+6
      float row[7] = {A.x, A.y, A.z, A.w, B.y, B.z, B.w};
      #pragma unroll
      for (int odp = 0; odp < 2; ++odp) {
        int kd = dd - 2 * odp;
        if (kd < 0 || kd > 4) continue;       // folds at compile time
        #pragma unroll
        for (int ohp = 0; ohp < 2; ++ohp) {
          int kh = hh - ohp;
          if (kh < 0 || kh > 2) continue;     // folds at compile time
          #pragma unroll
          for (int owp = 0; owp < 2; ++owp) {
            float a = c[odp][ohp][owp];
            #pragma unroll
            for (int kw = 0; kw < 5; ++kw)
              a = fmaf(row[2 * owp + kw], wq[kd * 15 + kh * 5 + kw], a);
            c[odp][ohp][owp] = a;
          }
        }
      }
    }
  }
  float m = ((float*)c)[0];
  #pragma unroll
  for (int i = 1; i < 8; ++i) m = fmaxf(m, ((float*)c)[i]);
  feat_g[(size_t)batch * 344 + rr] = m + bc;
  if (rr == 0) feat_g[(size_t)batch * 344 + 343] = 0.f;  // pad for FC1 quads
}

// FC1+FC2+softmax, 2 batches per block (1024 blocks -> 4 blocks/CU,
// 16 waves/CU: 2x R7's TLP for latency hiding). w1T quad loaded once,
// fma'd into 2 batch accumulators. Per-batch fma order byte-identical to
// the proven kernel -> absmax 0.
__global__ __launch_bounds__(256) void fc_net(
    const float* __restrict__ ws, const float* __restrict__ bfc1,
    const float* __restrict__ bfc2, float* __restrict__ out) {
  __shared__ alignas(16) float feat[2][344];
  __shared__ float fc1p[2][128];
  __shared__ float a1[2][128];
  __shared__ float s2[2][4];
  int t = threadIdx.x;
  int b0 = blockIdx.x * 2;

  // stage 2 batches' feat (172 f4) -> LDS
  {
    const float4* src = (const float4*)(ws + WS_FEAT + (size_t)b0 * 344);
    float4* dst = (float4*)&feat[0][0];
    if (t < 172) dst[t] = src[t];
  }
  __syncthreads();

  // FC1: g = j-half, o = output; 43 quads per half (g=1 tail uses
  // feat[343]=0; w1T row 343 lands in finite W2 region * 0.0 -> exact).
  int g = t >> 7, o = t & 127;
  {
    const float* wp = ws + WS_W1T + (g ? 172 * 128 : 0) + o;
    int j0 = g ? 172 : 0;
    float q0[2], q1[2], q2[2], q3[2];
    #pragma unroll
    for (int bb = 0; bb < 2; ++bb) { q0[bb] = q1[bb] = q2[bb] = q3[bb] = 0.f; }
    for (int k = 0; k < 43; ++k) {
      float w0 = wp[0], w1 = wp[128], w2 = wp[256], w3 = wp[384];
      #pragma unroll
      for (int bb = 0; bb < 2; ++bb) {
        float4 ff = *(const float4*)&feat[bb][j0 + k * 4];
        q0[bb] = fmaf(ff.x, w0, q0[bb]);
        q1[bb] = fmaf(ff.y, w1, q1[bb]);
        q2[bb] = fmaf(ff.z, w2, q2[bb]);
        q3[bb] = fmaf(ff.w, w3, q3[bb]);
      }
      wp += 512;
    }
    #pragma unroll
    for (int bb = 0; bb < 2; ++bb) {
      float acc = (q0[bb] + q1[bb]) + (q2[bb] + q3[bb]);
      if (g) fc1p[bb][o] = acc;
      else   a1[bb][o] = acc;                 // partial; finished below
    }
    __syncthreads();
    #pragma unroll
    for (int bb = 0; bb < 2; ++bb)
      if (!g) a1[bb][o] = fmaxf(a1[bb][o] + fc1p[bb][o] + bfc1[o], 0.f);
  }
  __syncthreads();

  // FC2: waves 0,1 handle batches 0,1; lane l=(kk,cls), shuffle-reduce.
  if (t < 128) {
    int w = t >> 6, l = t & 63;
    int cls = l & 3, kk = l >> 2;             // kk 0..15, 8 k's each
    const float* w2p = ws + WS_W2 + cls * 128 + kk * 8;
    const float* av = &a1[w][kk * 8];
    float p = 0.f;
    #pragma unroll
    for (int i = 0; i < 8; ++i) p = fmaf(av[i], w2p[i], p);
    p += __shfl_down(p, 32);
    p += __shfl_down(p, 16);
    p += __shfl_down(p, 8);
    p += __shfl_down(p, 4);
    if (l < 4) s2[w][l] = p + bfc2[l];
  }
  __syncthreads();
  // softmax + store: thread t<8 -> (batch w, class cls)
  if (t < 8) {
    int w = t >> 2, cls = t & 3;
    float v0 = s2[w][0], v1 = s2[w][1], v2 = s2[w][2], v3 = s2[w][3];
    float m = fmaxf(fmaxf(v0, v1), fmaxf(v2, v3));
    float e0 = expf(v0 - m), e1 = expf(v1 - m);
    float e2 = expf(v2 - m), e3 = expf(v3 - m);
    float inv = 1.f / (e0 + e1 + e2 + e3);
    float mine = (cls == 0) ? e0 : (cls == 1) ? e1 : (cls == 2) ? e2 : e3;
    out[(b0 + w) * 4 + cls] = mine * inv;
  }
}

extern "C" void kernel_launch(void* const* d_in, const int* in_sizes, int n_in,
                              void* d_out, int out_size, void* d_ws, size_t ws_size,
                              hipStream_t stream) {
  const float* x     = (const float*)d_in[0];
  const float* wconv = (const float*)d_in[1];
  const float* bconv = (const float*)d_in[2];
  const float* wfc1  = (const float*)d_in[3];
  const float* bfc1  = (const float*)d_in[4];
  const float* wfc2  = (const float*)d_in[5];
  const float* bfc2  = (const float*)d_in[6];
  float* out = (float*)d_out;
  float* ws  = (float*)d_ws;

  quant_all<<<89, 256, 0, stream>>>(wconv, wfc1, wfc2, ws);
  conv_pool<<<2744, 256, 0, stream>>>(x, bconv, ws, ws + WS_FEAT);
  fc_net<<<1024, 256, 0, stream>>>(ws, bfc1, bfc2, out);
}